// Round 16
// baseline (813.712 us; speedup 1.0000x reference)
//
#include <hip/hip_runtime.h>
#include <hip/hip_bf16.h>
#include <stdint.h>

typedef __attribute__((ext_vector_type(4))) float f32x4;
typedef __attribute__((ext_vector_type(16))) float f32x16;
typedef __attribute__((ext_vector_type(8))) short bf16x8;
typedef __attribute__((ext_vector_type(8))) unsigned short ushort8;
typedef __attribute__((ext_vector_type(4))) unsigned short ushort4v;

// round-to-nearest-even f32 -> bf16
__device__ __forceinline__ unsigned short f2bf(float f) {
    union { float f; unsigned int u; } v; v.f = f;
    unsigned int u = v.u;
    u += 0x7FFFu + ((u >> 16) & 1u);
    return (unsigned short)(u >> 16);
}

// legacy swizzle for the 128x128 fallback kernels
__device__ __forceinline__ int swz(int row, int k) {
    return (row * 64 + k) ^ ((row & 7) << 3);
}

__device__ __forceinline__ void gld16(const void* g, void* l) {
    __builtin_amdgcn_global_load_lds(
        (const __attribute__((address_space(1))) unsigned int*)g,
        (__attribute__((address_space(3))) unsigned int*)l,
        16, 0, 0);
}

// ---------------- fused prepass: blocks [0, deqB) dequant W; [deqB, ..) cvt X --
__global__ __launch_bounds__(256)
void prep(const float* __restrict__ X, const int* __restrict__ QW,
          const float* __restrict__ SC, const int* __restrict__ QZ,
          unsigned short* __restrict__ Xb, unsigned short* __restrict__ WT,
          int N, int K, long long n8, int deqB) {
    const int bid = blockIdx.x;
    const int t = threadIdx.x;
    if (bid < deqB) {
        const int ntiles = N >> 6;
        const int nb = bid % ntiles;
        const int kb = bid / ntiles;
        const int n0 = nb * 64, kp0 = kb * 64;
        #pragma unroll
        for (int w = 0; w < 16; ++w) {
            const int p = t + 256 * w;
            const int kpo = p & 63, ni = p >> 6;
            const int n = n0 + ni, kp = kp0 + kpo;
            const int g = kp >> 4;
            const float s = SC[(size_t)g * N + n];
            const int zq = ((QZ[(size_t)g * (N >> 3) + (n >> 3)] >> ((n & 7) * 4)) & 15) + 1;
            const float zb = -(float)zq * s;
            const unsigned int q = (unsigned int)QW[(size_t)kp * N + n];
            ushort8 o;
            #pragma unroll
            for (int j = 0; j < 8; ++j)
                o[j] = f2bf(fmaf((float)((q >> (4 * j)) & 15u), s, zb));
            *reinterpret_cast<ushort8*>(&WT[(size_t)n * K + kp * 8]) = o;
        }
    } else {
        long long i0 = (long long)(bid - deqB) * 256 + t;
        long long stride = (long long)(gridDim.x - deqB) * 256;
        for (long long i = i0; i < n8; i += stride) {
            const float4* p = reinterpret_cast<const float4*>(X + i * 8);
            float4 a = p[0], b = p[1];
            ushort8 o;
            o[0] = f2bf(a.x); o[1] = f2bf(a.y); o[2] = f2bf(a.z); o[3] = f2bf(a.w);
            o[4] = f2bf(b.x); o[5] = f2bf(b.y); o[6] = f2bf(b.z); o[7] = f2bf(b.w);
            *reinterpret_cast<ushort8*>(Xb + i * 8) = o;
        }
    }
}

// standalone prepasses (generic-shape fallback path)
__global__ __launch_bounds__(256)
void cvt_x(const float* __restrict__ X, unsigned short* __restrict__ Xb, long long n8) {
    long long i0 = (long long)blockIdx.x * 256 + threadIdx.x;
    long long stride = (long long)gridDim.x * 256;
    for (long long i = i0; i < n8; i += stride) {
        const float4* p = reinterpret_cast<const float4*>(X + i * 8);
        float4 a = p[0], b = p[1];
        ushort8 o;
        o[0] = f2bf(a.x); o[1] = f2bf(a.y); o[2] = f2bf(a.z); o[3] = f2bf(a.w);
        o[4] = f2bf(b.x); o[5] = f2bf(b.y); o[6] = f2bf(b.z); o[7] = f2bf(b.w);
        *reinterpret_cast<ushort8*>(Xb + i * 8) = o;
    }
}

__global__ __launch_bounds__(256)
void deq_w(const int* __restrict__ QW, const float* __restrict__ SC,
           const int* __restrict__ QZ, unsigned short* __restrict__ WT,
           int N, int K) {
    const int ntiles = N >> 6;
    const int nb = blockIdx.x % ntiles;
    const int kb = blockIdx.x / ntiles;
    const int n0 = nb * 64, kp0 = kb * 64;
    const int t = threadIdx.x;
    #pragma unroll
    for (int w = 0; w < 16; ++w) {
        const int p = t + 256 * w;
        const int kpo = p & 63, ni = p >> 6;
        const int n = n0 + ni, kp = kp0 + kpo;
        const int g = kp >> 4;
        const float s = SC[(size_t)g * N + n];
        const int zq = ((QZ[(size_t)g * (N >> 3) + (n >> 3)] >> ((n & 7) * 4)) & 15) + 1;
        const float zb = -(float)zq * s;
        const unsigned int q = (unsigned int)QW[(size_t)kp * N + n];
        ushort8 o;
        #pragma unroll
        for (int j = 0; j < 8; ++j)
            o[j] = f2bf(fmaf((float)((q >> (4 * j)) & 15u), s, zb));
        *reinterpret_cast<ushort8*>(&WT[(size_t)n * K + kp * 8]) = o;
    }
}

// ---------------- main GEMM: 256x256x64, 32x32x16 MFMA, conflict-free layout --
// 8 waves (2M x 4N), per-wave 128x64 output as 4m x 2n frags of 32x32.
// LDS half-tile layout (8192 elems, 128 rows x 64 k): 2 rows per 128-elem
// super-row with 4-bit XOR:
//   elem(row,k) = (row>>1)*128 + ((((row&1)<<3)|(k>>3)) ^ ((row>>1)&15))*8 + (k&7)
// A wave64 32-row x 2-k-octet read hits all 32 16B bank-slots exactly 2x ->
// conflict-free (fixes r5's 6.8e7 4-way conflict). Write side: LDS dest
// linear (tid*8), global source carries the inverse permutation (rule #21);
// the +4096 second gld16 maps to row+64 with identical lane formula.
// Schedule = r15 winner: pre-ph0 B-lo(t+1)->other; ph1 A-lo(t+2); ph2
// B-hi(t+2); ph3 A-hi(t+2); vmcnt(6) after quad42 (14 in flight -> retires
// exactly tile t+1). Early-issue reads; peak frag liveness 64 VGPR.
template<int KC, int NC>
__global__ __launch_bounds__(512, 2)
void qgemm_256(const unsigned short* __restrict__ Xb, const unsigned short* __restrict__ WT,
               const float* __restrict__ BIAS, float* __restrict__ OUT, int M) {
    __shared__ __align__(16) unsigned short S[65536];   // 128 KB

    int id = blockIdx.x;
    const int nwg = gridDim.x;
    if ((nwg & 7) == 0) id = (id & 7) * (nwg >> 3) + (id >> 3);   // XCD chunking

    constexpr int ntn = NC >> 8;
    const int bm = (id / ntn) << 8;
    const int bn = (id % ntn) << 8;
    const int tid = threadIdx.x;
    const int lane = tid & 63;
    const int wid = tid >> 6;
    const int wm = (wid >> 2) * 64;      // 0 / 64
    const int wn = (wid & 3) * 32;       // 0 / 32 / 64 / 96
    const int l31 = lane & 31;
    const int j0 = lane >> 5;            // k-octet within a K=16 step

    // read-side lane constants per fragment row-base (all multiples of 32):
    // row = rbase + l31; sr = row>>1; s0 = ((row&1)<<3) ^ (sr&15) ^ j0
    // frag addr(kk) = sr*128 + ((s0 ^ (kk<<1)) << 3)
    int offA0, s0A0, offA1, s0A1, offB0, s0B0;
    {
        int r0 = wm + l31;       offA0 = (r0 >> 1) * 128; s0A0 = ((r0 & 1) << 3) ^ ((r0 >> 1) & 15) ^ j0;
        int r1 = wm + 32 + l31;  offA1 = (r1 >> 1) * 128; s0A1 = ((r1 & 1) << 3) ^ ((r1 >> 1) & 15) ^ j0;
        int r2 = wn + l31;       offB0 = (r2 >> 1) * 128; s0B0 = ((r2 & 1) << 3) ^ ((r2 >> 1) & 15) ^ j0;
    }

    f32x16 acc[4][2] = {};
    constexpr int nk = KC >> 6;

    // staging lane constants: inverse permutation of the layout above
    const int u = (tid & 15) ^ ((tid >> 4) & 15);
    const int srow = ((tid >> 4) << 1) | (u >> 3);
    const int scol = (u & 7) << 3;
    const unsigned short* gA[2] = { Xb + (size_t)(bm + srow) * KC + scol,
                                    Xb + (size_t)(bm + 128 + srow) * KC + scol };
    const unsigned short* gB[2] = { WT + (size_t)(bn + srow) * KC + scol,
                                    WT + (size_t)(bn + 128 + srow) * KC + scol };

    auto stage = [&](int buf, int tt, int kind, int half) {
        const unsigned short* g = (kind ? gB[half] : gA[half]) + (size_t)tt * 64;
        unsigned short* lb = S + (kind ? 32768 : 0) + buf * 16384 + half * 8192 + tid * 8;
        gld16(g, lb);
        gld16(g + (size_t)64 * KC, lb + 4096);   // rows +64, same lane formula
    };

    bf16x8 aL[2][4], aH[2][4], bL[4], bH[4];

    auto loadApair = [&](bf16x8 (&dst)[2][4], const unsigned short* base) {
        #pragma unroll
        for (int kk = 0; kk < 4; ++kk) {
            dst[0][kk] = *reinterpret_cast<const bf16x8*>(base + offA0 + ((s0A0 ^ (kk << 1)) << 3));
            dst[1][kk] = *reinterpret_cast<const bf16x8*>(base + offA1 + ((s0A1 ^ (kk << 1)) << 3));
        }
    };
    auto loadBv = [&](bf16x8 (&dst)[4], const unsigned short* base) {
        #pragma unroll
        for (int kk = 0; kk < 4; ++kk)
            dst[kk] = *reinterpret_cast<const bf16x8*>(base + offB0 + ((s0B0 ^ (kk << 1)) << 3));
    };
    auto quad = [&](bf16x8 (&A)[2][4], bf16x8 (&B)[4], int m0, int nf) {
        __builtin_amdgcn_s_setprio(1);
        #pragma unroll
        for (int kk = 0; kk < 4; ++kk)
            #pragma unroll
            for (int m = 0; m < 2; ++m)
                acc[m0 + m][nf] = __builtin_amdgcn_mfma_f32_32x32x16_bf16(
                    A[m][kk], B[kk], acc[m0 + m][nf], 0, 0, 0);
        __builtin_amdgcn_s_setprio(0);
    };

    // prologue: tile0 all 4 halves -> buf0; tile1's A-lo, B-hi, A-hi -> buf1
    stage(0, 0, 0, 0); stage(0, 0, 0, 1);
    stage(0, 0, 1, 0); stage(0, 0, 1, 1);
    stage(1, 1, 0, 0); stage(1, 1, 1, 1); stage(1, 1, 0, 1);
    asm volatile("s_waitcnt vmcnt(6)" ::: "memory");   // tile0's 8 retired

    for (int t = 0; t < nk; ++t) {
        const int c = t & 1;
        const unsigned short* Sa = S + c * 16384;
        const unsigned short* Sb = S + 32768 + c * 16384;

        // ---- pre-ph0: stage B-lo(t+1) -> other buf (region idle since t-1 ph1)
        if (t + 1 < nk) stage(c ^ 1, t + 1, 1, 0);

        // ---- ph0: read aL, bL, AND bH (early); quad(aL,bL)
        __builtin_amdgcn_s_barrier();
        loadApair(aL, Sa);
        loadBv(bL, Sb);
        loadBv(bH, Sb + 8192);              // early issue: feeds ph1's quad
        quad(aL, bL, 0, 0);
        __builtin_amdgcn_s_barrier();

        // ---- ph1: stage A-lo(t+2); quad(aL,bH); read aH after aL dies
        if (t + 2 < nk) stage(c, t + 2, 0, 0);
        quad(aL, bH, 0, 1);                 // aL dies here
        loadApair(aH, Sa + 8192);           // early issue: feeds ph2's quad
        __builtin_amdgcn_s_barrier();

        // ---- ph2: stage B-hi(t+2); quad(aH,bL)
        if (t + 2 < nk) stage(c, t + 2, 1, 1);
        quad(aH, bL, 2, 0);                 // bL dies here
        __builtin_amdgcn_s_barrier();

        // ---- ph3: stage A-hi(t+2); quad(aH,bH); vmcnt after (overlap w/ MFMA)
        if (t + 2 < nk) {
            stage(c, t + 2, 0, 1);
            quad(aH, bH, 2, 1);
            asm volatile("s_waitcnt vmcnt(6)" ::: "memory");   // tile t+1 resident
        } else {
            quad(aH, bH, 2, 1);
            asm volatile("s_waitcnt vmcnt(0)" ::: "memory");
        }
    }

    // epilogue: 32x32 C/D layout (verified r5): col = lane&31,
    // row = (reg&3) + 8*(reg>>2) + 4*(lane>>5)
    #pragma unroll
    for (int mf = 0; mf < 4; ++mf) {
        const int rb = bm + (mf >> 1) * 128 + wm + (mf & 1) * 32 + (lane >> 5) * 4;
        #pragma unroll
        for (int nf = 0; nf < 2; ++nf) {
            const int col = bn + nf * 128 + wn + l31;
            const float bv = BIAS[col];
            #pragma unroll
            for (int q = 0; q < 4; ++q)
                #pragma unroll
                for (int r = 0; r < 4; ++r)
                    OUT[(size_t)(rb + q * 8 + r) * NC + col] = acc[mf][nf][q * 4 + r] + bv;
        }
    }
}

// ---------------- 128x128 dbuf GEMM (proven; generic-shape fallback) ----------------
__global__ __launch_bounds__(256, 2)
void qgemm_ws(const unsigned short* __restrict__ Xb, const unsigned short* __restrict__ WT,
              const float* __restrict__ BIAS, float* __restrict__ OUT,
              int M, int N, int K) {
    __shared__ __align__(16) unsigned short As[2][128 * 64];
    __shared__ __align__(16) unsigned short Bs[2][128 * 64];

    const int ntn = N >> 7;
    const int bm = (blockIdx.x / ntn) * 128;
    const int bn = (blockIdx.x % ntn) * 128;
    const int tid = threadIdx.x;
    const int lane = tid & 63;
    const int wave = tid >> 6;
    const int wm = (wave >> 1) * 64, wn = (wave & 1) * 64;
    const int lr = lane & 15, lk = (lane >> 4) * 8;

    f32x4 acc[4][4] = {};
    const int nk = K >> 6;

    auto stage = [&](int buf, int t) {
        const int k0 = t * 64;
        #pragma unroll
        for (int p = 0; p < 4; ++p) {
            const int slot = p * 256 + tid;
            const int row = slot >> 3, c = slot & 7;
            const int gk = k0 + ((c ^ (row & 7)) << 3);
            gld16(Xb + (size_t)(bm + row) * K + gk, &As[buf][slot * 8]);
            gld16(WT + (size_t)(bn + row) * K + gk, &Bs[buf][slot * 8]);
        }
    };

    auto compute = [&](int buf) {
        #pragma unroll
        for (int kk = 0; kk < 2; ++kk) {
            bf16x8 af[4], bfr[4];
            #pragma unroll
            for (int i = 0; i < 4; ++i) {
                af[i]  = *reinterpret_cast<const bf16x8*>(&As[buf][swz(wm + i * 16 + lr, kk * 32 + lk)]);
                bfr[i] = *reinterpret_cast<const bf16x8*>(&Bs[buf][swz(wn + i * 16 + lr, kk * 32 + lk)]);
            }
            #pragma unroll
            for (int i = 0; i < 4; ++i)
                #pragma unroll
                for (int j = 0; j < 4; ++j)
                    acc[i][j] = __builtin_amdgcn_mfma_f32_16x16x32_bf16(af[i], bfr[j], acc[i][j], 0, 0, 0);
        }
    };

    stage(0, 0);
    __syncthreads();
    int cur = 0;
    for (int t = 0; t < nk; ++t) {
        if (t + 1 < nk) stage(cur ^ 1, t + 1);
        compute(cur);
        __syncthreads();
        cur ^= 1;
    }

    #pragma unroll
    for (int i = 0; i < 4; ++i) {
        #pragma unroll
        for (int j = 0; j < 4; ++j) {
            const int col = bn + wn + j * 16 + lr;
            const float b = BIAS[col];
            #pragma unroll
            for (int r = 0; r < 4; ++r) {
                const int row = bm + wm + i * 16 + (lane >> 4) * 4 + r;
                OUT[(size_t)row * N + col] = acc[i][j][r] + b;
            }
        }
    }
}

// ---------------- fused fallback (ws too small) ----------------
__global__ __launch_bounds__(256, 2)
void qgemm_fb(const float* __restrict__ X, const int* __restrict__ QW,
              const float* __restrict__ SC, const int* __restrict__ QZ,
              const float* __restrict__ BIAS, float* __restrict__ OUT,
              int M, int N, int K) {
    __shared__ __align__(16) unsigned short As[2][128 * 64];
    __shared__ __align__(16) unsigned short Bs[2][128 * 64];

    const int ntn = N / 128;
    const int bm = (blockIdx.x / ntn) * 128;
    const int bn = (blockIdx.x % ntn) * 128;
    const int tid  = threadIdx.x;
    const int lane = tid & 63;
    const int wave = tid >> 6;
    const int wm = (wave >> 1) * 64, wn = (wave & 1) * 64;
    const int lr = lane & 15, lk = (lane >> 4) * 8;
    const int a_c4 = tid & 15, a_r0 = tid >> 4;
    const int b_n  = tid & 127, b_k0 = tid >> 7;

    f32x4 acc[4][4] = {};
    float4 va[8];
    unsigned int wb[4];
    float sc_s = 0.f, sc_zb = 0.f;
    const int nk = K / 64;

    auto gload = [&](int t) {
        const int k0 = t * 64;
        #pragma unroll
        for (int p = 0; p < 8; ++p)
            va[p] = *reinterpret_cast<const float4*>(X + (size_t)(bm + a_r0 + p * 16) * K + k0 + a_c4 * 4);
        const int g  = k0 >> 7;
        const int gn = bn + b_n;
        sc_s = SC[(size_t)g * N + gn];
        const int zq = ((QZ[(size_t)g * (N >> 3) + (gn >> 3)] >> ((gn & 7) * 4)) & 15) + 1;
        sc_zb = -(float)zq * sc_s;
        #pragma unroll
        for (int p = 0; p < 4; ++p)
            wb[p] = (unsigned int)QW[(size_t)(t * 8 + b_k0 + p * 2) * N + gn];
    };

    auto lwrite = [&](int buf) {
        #pragma unroll
        for (int p = 0; p < 8; ++p) {
            const int row = a_r0 + p * 16;
            ushort4v b;
            b.x = f2bf(va[p].x); b.y = f2bf(va[p].y);
            b.z = f2bf(va[p].z); b.w = f2bf(va[p].w);
            *reinterpret_cast<ushort4v*>(&As[buf][swz(row, a_c4 * 4)]) = b;
        }
        #pragma unroll
        for (int p = 0; p < 4; ++p) {
            const int ko = b_k0 + p * 2;
            ushort8 o;
            #pragma unroll
            for (int j = 0; j < 8; ++j)
                o[j] = f2bf(fmaf((float)((wb[p] >> (4 * j)) & 15u), sc_s, sc_zb));
            *reinterpret_cast<ushort8*>(&Bs[buf][swz(b_n, ko * 8)]) = o;
        }
    };

    auto compute = [&](int buf) {
        #pragma unroll
        for (int kk = 0; kk < 2; ++kk) {
            bf16x8 af[4], bfr[4];
            #pragma unroll
            for (int i = 0; i < 4; ++i) {
                af[i]  = *reinterpret_cast<const bf16x8*>(&As[buf][swz(wm + i * 16 + lr, kk * 32 + lk)]);
                bfr[i] = *reinterpret_cast<const bf16x8*>(&Bs[buf][swz(wn + i * 16 + lr, kk * 32 + lk)]);
            }
            #pragma unroll
            for (int i = 0; i < 4; ++i)
                #pragma unroll
                for (int j = 0; j < 4; ++j)
                    acc[i][j] = __builtin_amdgcn_mfma_f32_16x16x32_bf16(af[i], bfr[j], acc[i][j], 0, 0, 0);
        }
    };

    gload(0); lwrite(0);
    __syncthreads();
    for (int t = 0; t < nk; ++t) {
        if (t + 1 < nk) gload(t + 1);
        compute(t & 1);
        if (t + 1 < nk) lwrite((t + 1) & 1);
        __syncthreads();
    }

    #pragma unroll
    for (int i = 0; i < 4; ++i) {
        #pragma unroll
        for (int j = 0; j < 4; ++j) {
            const int col = bn + wn + j * 16 + lr;
            const float b = BIAS[col];
            #pragma unroll
            for (int r = 0; r < 4; ++r) {
                const int row = bm + wm + i * 16 + (lane >> 4) * 4 + r;
                OUT[(size_t)row * N + col] = acc[i][j][r] + b;
            }
        }
    }
}

extern "C" void kernel_launch(void* const* d_in, const int* in_sizes, int n_in,
                              void* d_out, int out_size, void* d_ws, size_t ws_size,
                              hipStream_t stream) {
    const float* X    = (const float*)d_in[0];
    const int*   QW   = (const int*)d_in[1];
    const float* SC   = (const float*)d_in[2];
    const int*   QZ   = (const int*)d_in[3];
    const float* BIAS = (const float*)d_in[4];
    float* OUT = (float*)d_out;

    const int N = in_sizes[4];
    const long long qwsz = in_sizes[1];
    const int K = (int)(qwsz * 8 / N);
    const int M = in_sizes[0] / K;

    const size_t xb_bytes = (size_t)M * K * 2;
    const size_t wt_bytes = (size_t)N * K * 2;

    if (ws_size >= xb_bytes + wt_bytes) {
        unsigned short* Xb = (unsigned short*)d_ws;
        unsigned short* WT = Xb + (size_t)M * K;

        if (K == 4096 && N == 11008 && (M % 256) == 0) {
            const int deqB = (N >> 6) * (K / 512);         // 1376
            prep<<<deqB + 2048, 256, 0, stream>>>(X, QW, SC, QZ, Xb, WT,
                                                  N, K, (long long)M * K / 8, deqB);
            qgemm_256<4096, 11008><<<(M / 256) * (11008 / 256), 512, 0, stream>>>(Xb, WT, BIAS, OUT, M);
        } else {
            cvt_x<<<2048, 256, 0, stream>>>(X, Xb, (long long)M * K / 8);
            deq_w<<<(N >> 6) * (K / 512), 256, 0, stream>>>(QW, SC, QZ, WT, N, K);
            qgemm_ws<<<(M / 128) * (N / 128), 256, 0, stream>>>(Xb, WT, BIAS, OUT, M, N, K);
        }
    } else {
        qgemm_fb<<<(M / 128) * (N / 128), 256, 0, stream>>>(X, QW, SC, QZ, BIAS, OUT, M, N, K);
    }
}

// Round 17
// 735.291 us; speedup vs baseline: 1.1067x; 1.1067x over previous
//
#include <hip/hip_runtime.h>
#include <hip/hip_bf16.h>
#include <stdint.h>

typedef __attribute__((ext_vector_type(4))) float f32x4;
typedef __attribute__((ext_vector_type(8))) short bf16x8;
typedef __attribute__((ext_vector_type(8))) unsigned short ushort8;
typedef __attribute__((ext_vector_type(4))) unsigned short ushort4v;

// round-to-nearest-even f32 -> bf16
__device__ __forceinline__ unsigned short f2bf(float f) {
    union { float f; unsigned int u; } v; v.f = f;
    unsigned int u = v.u;
    u += 0x7FFFu + ((u >> 16) & 1u);
    return (unsigned short)(u >> 16);
}

// swizzled element index in a [rows][64] bf16 tile: elem ^= (row&7)<<3
__device__ __forceinline__ int swz(int row, int k) {
    return (row * 64 + k) ^ ((row & 7) << 3);
}

__device__ __forceinline__ void gld16(const void* g, void* l) {
    __builtin_amdgcn_global_load_lds(
        (const __attribute__((address_space(1))) unsigned int*)g,
        (__attribute__((address_space(3))) unsigned int*)l,
        16, 0, 0);
}

// ---------------- fused prepass: blocks [0, deqB) dequant W; [deqB, ..) cvt X --
__global__ __launch_bounds__(256)
void prep(const float* __restrict__ X, const int* __restrict__ QW,
          const float* __restrict__ SC, const int* __restrict__ QZ,
          unsigned short* __restrict__ Xb, unsigned short* __restrict__ WT,
          int N, int K, long long n8, int deqB) {
    const int bid = blockIdx.x;
    const int t = threadIdx.x;
    if (bid < deqB) {
        const int ntiles = N >> 6;
        const int nb = bid % ntiles;
        const int kb = bid / ntiles;
        const int n0 = nb * 64, kp0 = kb * 64;
        #pragma unroll
        for (int w = 0; w < 16; ++w) {
            const int p = t + 256 * w;
            const int kpo = p & 63, ni = p >> 6;
            const int n = n0 + ni, kp = kp0 + kpo;
            const int g = kp >> 4;
            const float s = SC[(size_t)g * N + n];
            const int zq = ((QZ[(size_t)g * (N >> 3) + (n >> 3)] >> ((n & 7) * 4)) & 15) + 1;
            const float zb = -(float)zq * s;
            const unsigned int q = (unsigned int)QW[(size_t)kp * N + n];
            ushort8 o;
            #pragma unroll
            for (int j = 0; j < 8; ++j)
                o[j] = f2bf(fmaf((float)((q >> (4 * j)) & 15u), s, zb));
            *reinterpret_cast<ushort8*>(&WT[(size_t)n * K + kp * 8]) = o;
        }
    } else {
        long long i0 = (long long)(bid - deqB) * 256 + t;
        long long stride = (long long)(gridDim.x - deqB) * 256;
        for (long long i = i0; i < n8; i += stride) {
            const float4* p = reinterpret_cast<const float4*>(X + i * 8);
            float4 a = p[0], b = p[1];
            ushort8 o;
            o[0] = f2bf(a.x); o[1] = f2bf(a.y); o[2] = f2bf(a.z); o[3] = f2bf(a.w);
            o[4] = f2bf(b.x); o[5] = f2bf(b.y); o[6] = f2bf(b.z); o[7] = f2bf(b.w);
            *reinterpret_cast<ushort8*>(Xb + i * 8) = o;
        }
    }
}

// standalone prepasses (generic-shape fallback path)
__global__ __launch_bounds__(256)
void cvt_x(const float* __restrict__ X, unsigned short* __restrict__ Xb, long long n8) {
    long long i0 = (long long)blockIdx.x * 256 + threadIdx.x;
    long long stride = (long long)gridDim.x * 256;
    for (long long i = i0; i < n8; i += stride) {
        const float4* p = reinterpret_cast<const float4*>(X + i * 8);
        float4 a = p[0], b = p[1];
        ushort8 o;
        o[0] = f2bf(a.x); o[1] = f2bf(a.y); o[2] = f2bf(a.z); o[3] = f2bf(a.w);
        o[4] = f2bf(b.x); o[5] = f2bf(b.y); o[6] = f2bf(b.z); o[7] = f2bf(b.w);
        *reinterpret_cast<ushort8*>(Xb + i * 8) = o;
    }
}

__global__ __launch_bounds__(256)
void deq_w(const int* __restrict__ QW, const float* __restrict__ SC,
           const int* __restrict__ QZ, unsigned short* __restrict__ WT,
           int N, int K) {
    const int ntiles = N >> 6;
    const int nb = blockIdx.x % ntiles;
    const int kb = blockIdx.x / ntiles;
    const int n0 = nb * 64, kp0 = kb * 64;
    const int t = threadIdx.x;
    #pragma unroll
    for (int w = 0; w < 16; ++w) {
        const int p = t + 256 * w;
        const int kpo = p & 63, ni = p >> 6;
        const int n = n0 + ni, kp = kp0 + kpo;
        const int g = kp >> 4;
        const float s = SC[(size_t)g * N + n];
        const int zq = ((QZ[(size_t)g * (N >> 3) + (n >> 3)] >> ((n & 7) * 4)) & 15) + 1;
        const float zb = -(float)zq * s;
        const unsigned int q = (unsigned int)QW[(size_t)kp * N + n];
        ushort8 o;
        #pragma unroll
        for (int j = 0; j < 8; ++j)
            o[j] = f2bf(fmaf((float)((q >> (4 * j)) & 15u), s, zb));
        *reinterpret_cast<ushort8*>(&WT[(size_t)n * K + kp * 8]) = o;
    }
}

// ---------------- main GEMM: 256x256x64, 4 barriers/tile, early-issue reads ---
// (round-15 winner, measured best: 744 us total, MfmaUtil 50-51%, 0 conflicts)
// 8 waves (2M x 4N), per-wave 128x64 output as 8x4 16x16 frags.
// Quad order (aL,bL)->(aL,bH)->(aH,bL)->(aH,bH).
// EARLY-ISSUE: bH read in ph0 (with aL,bL); aH read at END of ph1 (after
// quad02 kills aL). Peak frag liveness 64 VGPR; quads in ph1/ph2/ph3 start
// with operands already in registers - only ph0 pays LDS latency.
// Stage slots: pre-ph0: B-lo(t+1)->other; ph1: A-lo(t+2); ph2: B-hi(t+2);
//   ph3: A-hi(t+2); vmcnt(6) AFTER quad42 (in-flight 14 -> retires exactly
//   tile t+1's 8 loads).
template<int KC, int NC>
__global__ __launch_bounds__(512, 2)
void qgemm_256(const unsigned short* __restrict__ Xb, const unsigned short* __restrict__ WT,
               const float* __restrict__ BIAS, float* __restrict__ OUT, int M) {
    __shared__ __align__(16) unsigned short S[65536];   // 128 KB

    int id = blockIdx.x;
    const int nwg = gridDim.x;
    if ((nwg & 7) == 0) id = (id & 7) * (nwg >> 3) + (id >> 3);   // XCD chunking

    constexpr int ntn = NC >> 8;
    const int bm = (id / ntn) << 8;
    const int bn = (id % ntn) << 8;
    const int tid = threadIdx.x;
    const int lane = tid & 63;
    const int wid = tid >> 6;
    const int wm = (wid >> 2) * 64;      // 0 / 64
    const int wn = (wid & 3) * 32;       // 0 / 32 / 64 / 96
    const int lr = lane & 15;
    const int lk = (lane >> 4) * 8;

    // folded swizzle lane terms: elem = row*64 + (k ^ xr), row&7 == lr&7
    const int xr  = (lr & 7) << 3;
    const int lo0 = lk ^ xr;             // kk=0
    const int lo1 = (32 + lk) ^ xr;      // kk=1
    const int lrow = lr * 64;

    f32x4 acc[8][4] = {};
    constexpr int nk = KC >> 6;

    // staging per-thread constants (second row = row + 64; same col swizzle)
    const int srow = tid >> 3;
    const int scol = ((tid & 7) ^ (srow & 7)) << 3;
    const unsigned short* gA[2] = { Xb + (size_t)(bm + srow) * KC + scol,
                                    Xb + (size_t)(bm + 128 + srow) * KC + scol };
    const unsigned short* gB[2] = { WT + (size_t)(bn + srow) * KC + scol,
                                    WT + (size_t)(bn + 128 + srow) * KC + scol };

    auto stage = [&](int buf, int tt, int kind, int half) {
        const unsigned short* g = (kind ? gB[half] : gA[half]) + (size_t)tt * 64;
        unsigned short* lb = S + (kind ? 32768 : 0) + buf * 16384 + half * 8192 + tid * 8;
        gld16(g, lb);
        gld16(g + (size_t)64 * KC, lb + 4096);
    };

    bf16x8 aL[4][2], aH[4][2], bL[2][2], bH[2][2];

    auto loadA = [&](bf16x8 (&dst)[4][2], const unsigned short* Sa, int rbase) {
        const unsigned short* p = Sa + rbase * 64 + lrow;
        #pragma unroll
        for (int i = 0; i < 4; ++i) {
            dst[i][0] = *reinterpret_cast<const bf16x8*>(p + i * 1024 + lo0);
            dst[i][1] = *reinterpret_cast<const bf16x8*>(p + i * 1024 + lo1);
        }
    };
    auto loadB = [&](bf16x8 (&dst)[2][2], const unsigned short* Sb, int rbase) {
        const unsigned short* p = Sb + rbase * 64 + lrow;
        #pragma unroll
        for (int j = 0; j < 2; ++j) {
            dst[j][0] = *reinterpret_cast<const bf16x8*>(p + j * 1024 + lo0);
            dst[j][1] = *reinterpret_cast<const bf16x8*>(p + j * 1024 + lo1);
        }
    };
    auto quad = [&](bf16x8 (&A)[4][2], bf16x8 (&B)[2][2], int mi0, int nj0) {
        __builtin_amdgcn_s_setprio(1);
        #pragma unroll
        for (int kk = 0; kk < 2; ++kk)
            #pragma unroll
            for (int i = 0; i < 4; ++i)
                #pragma unroll
                for (int j = 0; j < 2; ++j)
                    acc[mi0 + i][nj0 + j] = __builtin_amdgcn_mfma_f32_16x16x32_bf16(
                        A[i][kk], B[j][kk], acc[mi0 + i][nj0 + j], 0, 0, 0);
        __builtin_amdgcn_s_setprio(0);
    };

    // prologue: tile0 all 4 halves -> buf0; tile1's A-lo, B-hi, A-hi -> buf1
    stage(0, 0, 0, 0); stage(0, 0, 0, 1);
    stage(0, 0, 1, 0); stage(0, 0, 1, 1);
    stage(1, 1, 0, 0); stage(1, 1, 1, 1); stage(1, 1, 0, 1);
    asm volatile("s_waitcnt vmcnt(6)" ::: "memory");   // tile0's 8 retired

    for (int t = 0; t < nk; ++t) {
        const int c = t & 1;
        const unsigned short* Sa = S + c * 16384;
        const unsigned short* Sb = S + 32768 + c * 16384;

        // ---- pre-ph0: stage B-lo(t+1) -> other buf (region idle since t-1 ph1)
        if (t + 1 < nk) stage(c ^ 1, t + 1, 1, 0);

        // ---- ph0: read aL, bL, AND bH (early); quad00
        __builtin_amdgcn_s_barrier();
        loadA(aL, Sa, wm);
        loadB(bL, Sb, wn);
        loadB(bH, Sb, 128 + wn);            // early issue: feeds quad02 next phase
        quad(aL, bL, 0, 0);
        __builtin_amdgcn_s_barrier();

        // ---- ph1: stage A-lo(t+2); quad02 (operands ready); read aH after aL dies
        if (t + 2 < nk) stage(c, t + 2, 0, 0);
        quad(aL, bH, 0, 2);                 // aL dies here
        loadA(aH, Sa, 128 + wm);            // early issue: feeds quad40 next phase
        __builtin_amdgcn_s_barrier();

        // ---- ph2: stage B-hi(t+2); quad40 (operands ready)
        if (t + 2 < nk) stage(c, t + 2, 1, 1);
        quad(aH, bL, 4, 0);                 // bL dies here
        __builtin_amdgcn_s_barrier();

        // ---- ph3: stage A-hi(t+2); quad42; vmcnt after (overlaps wait w/ MFMA)
        if (t + 2 < nk) {
            stage(c, t + 2, 0, 1);
            quad(aH, bH, 4, 2);
            asm volatile("s_waitcnt vmcnt(6)" ::: "memory");   // tile t+1 resident
        } else {
            quad(aH, bH, 4, 2);
            asm volatile("s_waitcnt vmcnt(0)" ::: "memory");
        }
    }

    // epilogue: C/D layout col=lane&15, row=(lane>>4)*4+reg
    #pragma unroll
    for (int mi = 0; mi < 8; ++mi) {
        const int row = bm + wm + (mi & 3) * 16 + ((mi >> 2) ? 128 : 0) + (lane >> 4) * 4;
        #pragma unroll
        for (int nj = 0; nj < 4; ++nj) {
            const int col = bn + wn + (nj & 1) * 16 + ((nj >> 1) ? 128 : 0) + lr;
            const float b = BIAS[col];
            #pragma unroll
            for (int r = 0; r < 4; ++r)
                OUT[(size_t)(row + r) * NC + col] = acc[mi][nj][r] + b;
        }
    }
}

// ---------------- 128x128 dbuf GEMM (proven; generic-shape fallback) ----------------
__global__ __launch_bounds__(256, 2)
void qgemm_ws(const unsigned short* __restrict__ Xb, const unsigned short* __restrict__ WT,
              const float* __restrict__ BIAS, float* __restrict__ OUT,
              int M, int N, int K) {
    __shared__ __align__(16) unsigned short As[2][128 * 64];
    __shared__ __align__(16) unsigned short Bs[2][128 * 64];

    const int ntn = N >> 7;
    const int bm = (blockIdx.x / ntn) * 128;
    const int bn = (blockIdx.x % ntn) * 128;
    const int tid = threadIdx.x;
    const int lane = tid & 63;
    const int wave = tid >> 6;
    const int wm = (wave >> 1) * 64, wn = (wave & 1) * 64;
    const int lr = lane & 15, lk = (lane >> 4) * 8;

    f32x4 acc[4][4] = {};
    const int nk = K >> 6;

    auto stage = [&](int buf, int t) {
        const int k0 = t * 64;
        #pragma unroll
        for (int p = 0; p < 4; ++p) {
            const int slot = p * 256 + tid;
            const int row = slot >> 3, c = slot & 7;
            const int gk = k0 + ((c ^ (row & 7)) << 3);
            gld16(Xb + (size_t)(bm + row) * K + gk, &As[buf][slot * 8]);
            gld16(WT + (size_t)(bn + row) * K + gk, &Bs[buf][slot * 8]);
        }
    };

    auto compute = [&](int buf) {
        #pragma unroll
        for (int kk = 0; kk < 2; ++kk) {
            bf16x8 af[4], bfr[4];
            #pragma unroll
            for (int i = 0; i < 4; ++i) {
                af[i]  = *reinterpret_cast<const bf16x8*>(&As[buf][swz(wm + i * 16 + lr, kk * 32 + lk)]);
                bfr[i] = *reinterpret_cast<const bf16x8*>(&Bs[buf][swz(wn + i * 16 + lr, kk * 32 + lk)]);
            }
            #pragma unroll
            for (int i = 0; i < 4; ++i)
                #pragma unroll
                for (int j = 0; j < 4; ++j)
                    acc[i][j] = __builtin_amdgcn_mfma_f32_16x16x32_bf16(af[i], bfr[j], acc[i][j], 0, 0, 0);
        }
    };

    stage(0, 0);
    __syncthreads();
    int cur = 0;
    for (int t = 0; t < nk; ++t) {
        if (t + 1 < nk) stage(cur ^ 1, t + 1);
        compute(cur);
        __syncthreads();
        cur ^= 1;
    }

    #pragma unroll
    for (int i = 0; i < 4; ++i) {
        #pragma unroll
        for (int j = 0; j < 4; ++j) {
            const int col = bn + wn + j * 16 + lr;
            const float b = BIAS[col];
            #pragma unroll
            for (int r = 0; r < 4; ++r) {
                const int row = bm + wm + i * 16 + (lane >> 4) * 4 + r;
                OUT[(size_t)row * N + col] = acc[i][j][r] + b;
            }
        }
    }
}

// ---------------- fused fallback (ws too small) ----------------
__global__ __launch_bounds__(256, 2)
void qgemm_fb(const float* __restrict__ X, const int* __restrict__ QW,
              const float* __restrict__ SC, const int* __restrict__ QZ,
              const float* __restrict__ BIAS, float* __restrict__ OUT,
              int M, int N, int K) {
    __shared__ __align__(16) unsigned short As[2][128 * 64];
    __shared__ __align__(16) unsigned short Bs[2][128 * 64];

    const int ntn = N / 128;
    const int bm = (blockIdx.x / ntn) * 128;
    const int bn = (blockIdx.x % ntn) * 128;
    const int tid  = threadIdx.x;
    const int lane = tid & 63;
    const int wave = tid >> 6;
    const int wm = (wave >> 1) * 64, wn = (wave & 1) * 64;
    const int lr = lane & 15, lk = (lane >> 4) * 8;
    const int a_c4 = tid & 15, a_r0 = tid >> 4;
    const int b_n  = tid & 127, b_k0 = tid >> 7;

    f32x4 acc[4][4] = {};
    float4 va[8];
    unsigned int wb[4];
    float sc_s = 0.f, sc_zb = 0.f;
    const int nk = K / 64;

    auto gload = [&](int t) {
        const int k0 = t * 64;
        #pragma unroll
        for (int p = 0; p < 8; ++p)
            va[p] = *reinterpret_cast<const float4*>(X + (size_t)(bm + a_r0 + p * 16) * K + k0 + a_c4 * 4);
        const int g  = k0 >> 7;
        const int gn = bn + b_n;
        sc_s = SC[(size_t)g * N + gn];
        const int zq = ((QZ[(size_t)g * (N >> 3) + (gn >> 3)] >> ((gn & 7) * 4)) & 15) + 1;
        sc_zb = -(float)zq * sc_s;
        #pragma unroll
        for (int p = 0; p < 4; ++p)
            wb[p] = (unsigned int)QW[(size_t)(t * 8 + b_k0 + p * 2) * N + gn];
    };

    auto lwrite = [&](int buf) {
        #pragma unroll
        for (int p = 0; p < 8; ++p) {
            const int row = a_r0 + p * 16;
            ushort4v b;
            b.x = f2bf(va[p].x); b.y = f2bf(va[p].y);
            b.z = f2bf(va[p].z); b.w = f2bf(va[p].w);
            *reinterpret_cast<ushort4v*>(&As[buf][swz(row, a_c4 * 4)]) = b;
        }
        #pragma unroll
        for (int p = 0; p < 4; ++p) {
            const int ko = b_k0 + p * 2;
            ushort8 o;
            #pragma unroll
            for (int j = 0; j < 8; ++j)
                o[j] = f2bf(fmaf((float)((wb[p] >> (4 * j)) & 15u), sc_s, sc_zb));
            *reinterpret_cast<ushort8*>(&Bs[buf][swz(b_n, ko * 8)]) = o;
        }
    };

    auto compute = [&](int buf) {
        #pragma unroll
        for (int kk = 0; kk < 2; ++kk) {
            bf16x8 af[4], bfr[4];
            #pragma unroll
            for (int i = 0; i < 4; ++i) {
                af[i]  = *reinterpret_cast<const bf16x8*>(&As[buf][swz(wm + i * 16 + lr, kk * 32 + lk)]);
                bfr[i] = *reinterpret_cast<const bf16x8*>(&Bs[buf][swz(wn + i * 16 + lr, kk * 32 + lk)]);
            }
            #pragma unroll
            for (int i = 0; i < 4; ++i)
                #pragma unroll
                for (int j = 0; j < 4; ++j)
                    acc[i][j] = __builtin_amdgcn_mfma_f32_16x16x32_bf16(af[i], bfr[j], acc[i][j], 0, 0, 0);
        }
    };

    gload(0); lwrite(0);
    __syncthreads();
    for (int t = 0; t < nk; ++t) {
        if (t + 1 < nk) gload(t + 1);
        compute(t & 1);
        if (t + 1 < nk) lwrite((t + 1) & 1);
        __syncthreads();
    }

    #pragma unroll
    for (int i = 0; i < 4; ++i) {
        #pragma unroll
        for (int j = 0; j < 4; ++j) {
            const int col = bn + wn + j * 16 + lr;
            const float b = BIAS[col];
            #pragma unroll
            for (int r = 0; r < 4; ++r) {
                const int row = bm + wm + i * 16 + (lane >> 4) * 4 + r;
                OUT[(size_t)row * N + col] = acc[i][j][r] + b;
            }
        }
    }
}

extern "C" void kernel_launch(void* const* d_in, const int* in_sizes, int n_in,
                              void* d_out, int out_size, void* d_ws, size_t ws_size,
                              hipStream_t stream) {
    const float* X    = (const float*)d_in[0];
    const int*   QW   = (const int*)d_in[1];
    const float* SC   = (const float*)d_in[2];
    const int*   QZ   = (const int*)d_in[3];
    const float* BIAS = (const float*)d_in[4];
    float* OUT = (float*)d_out;

    const int N = in_sizes[4];
    const long long qwsz = in_sizes[1];
    const int K = (int)(qwsz * 8 / N);
    const int M = in_sizes[0] / K;

    const size_t xb_bytes = (size_t)M * K * 2;
    const size_t wt_bytes = (size_t)N * K * 2;

    if (ws_size >= xb_bytes + wt_bytes) {
        unsigned short* Xb = (unsigned short*)d_ws;
        unsigned short* WT = Xb + (size_t)M * K;

        if (K == 4096 && N == 11008 && (M % 256) == 0) {
            const int deqB = (N >> 6) * (K / 512);         // 1376
            prep<<<deqB + 2048, 256, 0, stream>>>(X, QW, SC, QZ, Xb, WT,
                                                  N, K, (long long)M * K / 8, deqB);
            qgemm_256<4096, 11008><<<(M / 256) * (11008 / 256), 512, 0, stream>>>(Xb, WT, BIAS, OUT, M);
        } else {
            cvt_x<<<2048, 256, 0, stream>>>(X, Xb, (long long)M * K / 8);
            deq_w<<<(N >> 6) * (K / 512), 256, 0, stream>>>(QW, SC, QZ, WT, N, K);
            qgemm_ws<<<(M / 128) * (N / 128), 256, 0, stream>>>(Xb, WT, BIAS, OUT, M, N, K);
        }
    } else {
        qgemm_fb<<<(M / 128) * (N / 128), 256, 0, stream>>>(X, QW, SC, QZ, BIAS, OUT, M, N, K);
    }
}